// Round 7
// baseline (493.175 us; speedup 1.0000x reference)
//
#include <hip/hip_runtime.h>

typedef __attribute__((ext_vector_type(8))) short bf16x8;
typedef __attribute__((ext_vector_type(16))) float f32x16;
typedef unsigned int u32;

#define LOG2E 1.44269504088896f

__device__ __forceinline__ short f2bf(float f) {
    union { float f; unsigned u; } v; v.f = f;
    unsigned r = v.u + 0x7fffu + ((v.u >> 16) & 1u);
    return (short)(r >> 16);
}

#if __has_builtin(__builtin_amdgcn_exp2f)
#define EXP2(x) __builtin_amdgcn_exp2f(x)
#else
#define EXP2(x) __builtin_exp2f(x)
#endif

__device__ __forceinline__ u32 pack_bf16_trunc(float lo, float hi) {
#if __has_builtin(__builtin_amdgcn_perm)
    return __builtin_amdgcn_perm(__float_as_uint(hi), __float_as_uint(lo), 0x07060302u);
#else
    return (__float_as_uint(hi) & 0xFFFF0000u) | (__float_as_uint(lo) >> 16);
#endif
}

__device__ __forceinline__ f32x16 zero16() {
    f32x16 v;
    #pragma unroll
    for (int i = 0; i < 16; ++i) v[i] = 0.f;
    return v;
}

__device__ __forceinline__ void gload16(const void* g, void* l) {
    __builtin_amdgcn_global_load_lds(
        (const __attribute__((address_space(1))) void*)g,
        (__attribute__((address_space(3))) void*)l, 16, 0, 0);
}

// ---------------- prep (identical to verified round-4 version) ----------------
// blocks 0..255  : per-center scalars (log2e-scaled): ns=-s*L, nscs=-s*||c||^2*L, ts=2s*L
// blocks 256..383: centers -> cfrag (bf16), 32x32x16 A-frag order: slot s=[c][ks][lane]
// blocks 384..447: W -> wfrag (bf16), 32x32x16 B-frag order: slot s=[c][ct][k2][lane]
__global__ __launch_bounds__(256) void rbf_prep(
    const float* __restrict__ centers, const float* __restrict__ sigmas,
    const float* __restrict__ W,
    short* __restrict__ cfrag, short* __restrict__ wfrag,
    float* __restrict__ ns, float* __restrict__ nscs, float* __restrict__ ts)
{
    const int tid = threadIdx.x;
    const int bid = blockIdx.x;
    if (bid < 256) {
        const int lane = tid & 63, w = tid >> 6;
        const int row = bid * 4 + w;
        const float4 v = ((const float4*)(centers + (size_t)row * 256))[lane];
        float s = v.x*v.x + v.y*v.y + v.z*v.z + v.w*v.w;
        #pragma unroll
        for (int off = 32; off >= 1; off >>= 1) s += __shfl_xor(s, off, 64);
        if (lane == 0) {
            const float sg = sigmas[row];
            ns[row]   = -sg * LOG2E;
            nscs[row] = -sg * s * LOG2E;
            ts[row]   = 2.0f * sg * LOG2E;
        }
    } else if (bid < 384) {
        const int s = (bid - 256) * 256 + tid;               // 0..32767
        const int c = s >> 10, ks = (s >> 6) & 15, lane = s & 63;
        const int m = c * 32 + (lane & 31);
        const int k = ks * 16 + (lane >> 5) * 8;
        const float4 a = *(const float4*)(centers + (size_t)m * 256 + k);
        const float4 b = *(const float4*)(centers + (size_t)m * 256 + k + 4);
        bf16x8 t;
        t[0]=f2bf(a.x); t[1]=f2bf(a.y); t[2]=f2bf(a.z); t[3]=f2bf(a.w);
        t[4]=f2bf(b.x); t[5]=f2bf(b.y); t[6]=f2bf(b.z); t[7]=f2bf(b.w);
        ((bf16x8*)cfrag)[s] = t;
    } else {
        const int s = (bid - 384) * 256 + tid;               // 0..16383
        const int c = s >> 9, ct = (s >> 7) & 3, k2 = (s >> 6) & 1, lane = s & 63;
        const int o = ct * 32 + (lane & 31);
        const int m = c * 32 + k2 * 16 + (lane >> 5) * 8;
        const float4 a = *(const float4*)(W + (size_t)o * 1024 + m);
        const float4 b = *(const float4*)(W + (size_t)o * 1024 + m + 4);
        bf16x8 t;
        t[0]=f2bf(a.x); t[1]=f2bf(a.y); t[2]=f2bf(a.z); t[3]=f2bf(a.w);
        t[4]=f2bf(b.x); t[5]=f2bf(b.y); t[6]=f2bf(b.z); t[7]=f2bf(b.w);
        ((bf16x8*)wfrag)[s] = t;
    }
}

// ---------------- main: center-split 8-wave blocks -> 16 waves/CU ----------------
// 512 blocks x 512 threads. Wave w: group g=w>>2 (centers g*512..g*512+511),
// row tile t4=w&3 (rows blockIdx*128 + t4*32). Per-chunk body = verified round-4
// code. C via per-group double-buffered global_load_lds; W direct from global
// (L1-served: all 16 waves/CU read the same 8KB/chunk). One barrier per chunk.
// Epilogue: group 1's partial acc summed into group 0 through the Cb LDS space.
__global__ __launch_bounds__(512, 4) void rbf_main(
    const float* __restrict__ x, const float* __restrict__ bvec,
    const short* __restrict__ cfrag, const short* __restrict__ wfrag,
    const float* __restrict__ ns, const float* __restrict__ nscs,
    const float* __restrict__ ts, float* __restrict__ out)
{
    __shared__ short Cb[2][2][8192];   // [group][buf][16 KB] = 64 KB

    const int tid = threadIdx.x;
    const int lane = tid & 63;
    const int l31 = lane & 31;
    const int hi = lane >> 5;
    const int w = tid >> 6;            // 0..7
    const int g = w >> 2;              // center group
    const int t4 = w & 3;              // row tile
    const int qb = blockIdx.x * 128 + t4 * 32;
    const int cg0 = g * 16;            // first 32-center chunk of this group

    // ---- stage this group's chunk 0 (DMA overlaps the X prologue) ----
    #pragma unroll
    for (int i = 0; i < 4; ++i) {
        const int f = t4 * 4 + i;
        gload16(cfrag + (size_t)cg0 * 8192 + (f * 64 + lane) * 8, &Cb[g][0][f * 512]);
    }

    // ---- X fragments (regs, reused over all 16 chunks) + row sum of squares ----
    bf16x8 xb[16];
    const float* xr = x + (size_t)(qb + l31) * 256 + hi * 8;
    float ss = 0.f;
    #pragma unroll
    for (int ks = 0; ks < 16; ++ks) {
        const float4 a = *(const float4*)(xr + ks * 16);
        const float4 b = *(const float4*)(xr + ks * 16 + 4);
        ss += a.x*a.x + a.y*a.y + a.z*a.z + a.w*a.w
            + b.x*b.x + b.y*b.y + b.z*b.z + b.w*b.w;
        bf16x8 tv;
        tv[0]=f2bf(a.x); tv[1]=f2bf(a.y); tv[2]=f2bf(a.z); tv[3]=f2bf(a.w);
        tv[4]=f2bf(b.x); tv[5]=f2bf(b.y); tv[6]=f2bf(b.z); tv[7]=f2bf(b.w);
        xb[ks] = tv;
    }
    ss += __shfl_xor(ss, 32, 64);
    const float xs = ss;

    f32x16 acc[4];
    #pragma unroll
    for (int ct = 0; ct < 4; ++ct) acc[ct] = zero16();

    __syncthreads();   // drains chunk-0 DMA for both groups

    int buf = 0;
    for (int ci = 0; ci < 16; ++ci) {
        const int c = cg0 + ci;        // global 32-center chunk index

        // ---- DMA next chunk into buf^1 (protected by end-of-previous barrier) ----
        if (ci < 15) {
            const short* csrc = cfrag + (size_t)(c + 1) * 8192;
            #pragma unroll
            for (int i = 0; i < 4; ++i) {
                const int f = t4 * 4 + i;
                gload16(csrc + (f * 64 + lane) * 8, &Cb[g][buf ^ 1][f * 512]);
            }
        }

        // ---- W B-frags direct from global (L1-shared across the CU's waves) ----
        bf16x8 wf[8];
        const bf16x8* wsrc = (const bf16x8*)wfrag + (size_t)c * 512 + lane;
        #pragma unroll
        for (int f = 0; f < 8; ++f) wf[f] = wsrc[f * 64];

        // ---- S = C-chunk . X^T (A from LDS, B from regs) ----
        f32x16 S = zero16();
        const bf16x8* cbl = (const bf16x8*)&Cb[g][buf][0] + lane;
        __builtin_amdgcn_s_setprio(1);
        #pragma unroll
        for (int ks = 0; ks < 16; ++ks)
            S = __builtin_amdgcn_mfma_f32_32x32x16_bf16(cbl[ks * 64], xb[ks], S, 0, 0, 0);
        __builtin_amdgcn_s_setprio(0);

        // ---- phi = exp2(ts*S + ns*xs + nscs); reg r -> m = (r&3)+8*(r>>2)+4*hi ----
        float p[16];
        #pragma unroll
        for (int g4 = 0; g4 < 4; ++g4) {
            const float4 a4 = *(const float4*)(ns   + c * 32 + g4 * 8 + hi * 4);
            const float4 b4 = *(const float4*)(nscs + c * 32 + g4 * 8 + hi * 4);
            const float4 c4 = *(const float4*)(ts   + c * 32 + g4 * 8 + hi * 4);
            const float* ap = (const float*)&a4;
            const float* bp = (const float*)&b4;
            const float* cp = (const float*)&c4;
            #pragma unroll
            for (int j = 0; j < 4; ++j) {
                const float tt = fmaf(cp[j], S[g4 * 4 + j], fmaf(ap[j], xs, bp[j]));
                p[g4 * 4 + j] = EXP2(tt);
            }
        }

        // ---- pack + half-exchange -> PV A-frags; accumulate ----
        __builtin_amdgcn_s_setprio(1);
        #pragma unroll
        for (int k2 = 0; k2 < 2; ++k2) {
            const int rb = k2 * 8;
            const u32 A = pack_bf16_trunc(p[rb + 0], p[rb + 1]);
            const u32 B = pack_bf16_trunc(p[rb + 2], p[rb + 3]);
            const u32 C = pack_bf16_trunc(p[rb + 4], p[rb + 5]);
            const u32 D = pack_bf16_trunc(p[rb + 6], p[rb + 7]);
            const u32 g0 = hi ? A : C;
            const u32 g1 = hi ? B : D;
            const u32 r0 = (u32)__shfl_xor((int)g0, 32, 64);
            const u32 r1 = (u32)__shfl_xor((int)g1, 32, 64);
            union { u32 u[4]; bf16x8 v; } pa;
            pa.u[0] = hi ? r0 : A;
            pa.u[1] = hi ? r1 : B;
            pa.u[2] = hi ? C : r0;
            pa.u[3] = hi ? D : r1;
            #pragma unroll
            for (int ct = 0; ct < 4; ++ct)
                acc[ct] = __builtin_amdgcn_mfma_f32_32x32x16_bf16(pa.v, wf[ct * 2 + k2], acc[ct], 0, 0, 0);
        }
        __builtin_amdgcn_s_setprio(0);

        __syncthreads();   // drains this chunk's DMA; all waves done with Cb[g][buf]
        buf ^= 1;
    }

    // ---- cross-group reduction through the (now free) Cb LDS space ----
    float* red = (float*)&Cb[0][0][0];   // 16384 floats = 64 KB
    if (g == 1) {
        #pragma unroll
        for (int ct = 0; ct < 4; ++ct)
            #pragma unroll
            for (int r = 0; r < 16; ++r)
                red[t4 * 4096 + ct * 1024 + r * 64 + lane] = acc[ct][r];
    }
    __syncthreads();
    if (g == 0) {
        float bq[4];
        #pragma unroll
        for (int ct = 0; ct < 4; ++ct) bq[ct] = bvec[ct * 32 + l31];
        #pragma unroll
        for (int r = 0; r < 16; ++r) {
            const int q = qb + (r & 3) + 8 * (r >> 2) + 4 * hi;
            #pragma unroll
            for (int ct = 0; ct < 4; ++ct)
                out[(size_t)q * 128 + ct * 32 + l31] =
                    acc[ct][r] + red[t4 * 4096 + ct * 1024 + r * 64 + lane] + bq[ct];
        }
    }
}

extern "C" void kernel_launch(void* const* d_in, const int* in_sizes, int n_in,
                              void* d_out, int out_size, void* d_ws, size_t ws_size,
                              hipStream_t stream) {
    (void)in_sizes; (void)n_in; (void)out_size; (void)ws_size;
    const float* x       = (const float*)d_in[0];
    const float* centers = (const float*)d_in[1];
    const float* sigmas  = (const float*)d_in[2];
    const float* W       = (const float*)d_in[3];
    const float* b       = (const float*)d_in[4];
    float* out = (float*)d_out;

    short* cfrag = (short*)d_ws;                 // 32768 frags * 16B = 512 KB
    short* wfrag = cfrag + 32768 * 8;            // 16384 frags * 16B = 256 KB
    float* ns    = (float*)(wfrag + 16384 * 8);  // 4 KB
    float* nscs  = ns + 1024;                    // 4 KB
    float* ts    = nscs + 1024;                  // 4 KB

    rbf_prep<<<448, 256, 0, stream>>>(centers, sigmas, W, cfrag, wfrag, ns, nscs, ts);
    rbf_main<<<512, 512, 0, stream>>>(x, b, cfrag, wfrag, ns, nscs, ts, out);
}

// Round 8
// 88.909 us; speedup vs baseline: 5.5470x; 5.5470x over previous
//
#include <hip/hip_runtime.h>

typedef __attribute__((ext_vector_type(8))) short bf16x8;
typedef __attribute__((ext_vector_type(16))) float f32x16;
typedef unsigned int u32;
typedef unsigned long long u64;

#define LOG2E 1.44269504088896f

__device__ __forceinline__ short f2bf(float f) {
    union { float f; unsigned u; } v; v.f = f;
    unsigned r = v.u + 0x7fffu + ((v.u >> 16) & 1u);
    return (short)(r >> 16);
}

// float -> OCP e4m3fn byte (RNE, saturate to 448)
__device__ __forceinline__ u32 f2e4m3(float f) {
    u32 u = __float_as_uint(f);
    u32 sgn = (u >> 24) & 0x80u;
    u32 mag = u & 0x7fffffffu;
    if (mag >= 0x43E00000u) return sgn | 0x7Eu;
    if (mag < 0x3C800000u) {
        u32 q = (u32)(__uint_as_float(mag) * 512.0f + 0.5f);
        return sgn | q;
    }
    u32 r = mag + 0x0007FFFFu + ((mag >> 20) & 1u);
    u32 e8 = ((r >> 23) - 120u) & 0xFu;
    u32 m3 = (r >> 20) & 7u;
    return sgn | (e8 << 3) | m3;
}

__device__ __forceinline__ long pack8_e4m3(float4 a, float4 b) {
    u32 lo = f2e4m3(a.x) | (f2e4m3(a.y) << 8) | (f2e4m3(a.z) << 16) | (f2e4m3(a.w) << 24);
    u32 hi = f2e4m3(b.x) | (f2e4m3(b.y) << 8) | (f2e4m3(b.z) << 16) | (f2e4m3(b.w) << 24);
    return (long)(((u64)hi << 32) | lo);
}

#if __has_builtin(__builtin_amdgcn_exp2f)
#define EXP2(x) __builtin_amdgcn_exp2f(x)
#else
#define EXP2(x) __builtin_exp2f(x)
#endif

__device__ __forceinline__ u32 pack_bf16_trunc(float lo, float hi) {
#if __has_builtin(__builtin_amdgcn_perm)
    return __builtin_amdgcn_perm(__float_as_uint(hi), __float_as_uint(lo), 0x07060302u);
#else
    return (__float_as_uint(hi) & 0xFFFF0000u) | (__float_as_uint(lo) >> 16);
#endif
}

__device__ __forceinline__ f32x16 zero16() {
    f32x16 v;
    #pragma unroll
    for (int i = 0; i < 16; ++i) v[i] = 0.f;
    return v;
}

__device__ __forceinline__ void gload16(const void* g, void* l) {
    __builtin_amdgcn_global_load_lds(
        (const __attribute__((address_space(1))) void*)g,
        (__attribute__((address_space(3))) void*)l, 16, 0, 0);
}

// ---------------- prep (r6-verified layouts) ----------------
// blocks 0..255  : per-center scalars (log2e-scaled): ns=-s*L, nscs=-s*||c||^2*L, ts=2s*L
// blocks 256..383: centers -> cfrag8 (fp8 e4m3), 32x32x16 fp8 A-frag order:
//                  slot s=[c][ks][lane] 8B: m=c*32+(l&31), k=ks*16+(l>>5)*8+j
// blocks 384..447: W -> wfrag (bf16), 32x32x16 B-frag order: slot s=[c][ct][k2][lane]
__global__ __launch_bounds__(256) void rbf_prep(
    const float* __restrict__ centers, const float* __restrict__ sigmas,
    const float* __restrict__ W,
    char* __restrict__ cfrag8, short* __restrict__ wfrag,
    float* __restrict__ ns, float* __restrict__ nscs, float* __restrict__ ts)
{
    const int tid = threadIdx.x;
    const int bid = blockIdx.x;
    if (bid < 256) {
        const int lane = tid & 63, w = tid >> 6;
        const int row = bid * 4 + w;
        const float4 v = ((const float4*)(centers + (size_t)row * 256))[lane];
        float s = v.x*v.x + v.y*v.y + v.z*v.z + v.w*v.w;
        #pragma unroll
        for (int off = 32; off >= 1; off >>= 1) s += __shfl_xor(s, off, 64);
        if (lane == 0) {
            const float sg = sigmas[row];
            ns[row]   = -sg * LOG2E;
            nscs[row] = -sg * s * LOG2E;
            ts[row]   = 2.0f * sg * LOG2E;
        }
    } else if (bid < 384) {
        const int s = (bid - 256) * 256 + tid;               // 0..32767
        const int c = s >> 10, ks = (s >> 6) & 15, lane = s & 63;
        const int m = c * 32 + (lane & 31);
        const int k = ks * 16 + (lane >> 5) * 8;
        const float4 a = *(const float4*)(centers + (size_t)m * 256 + k);
        const float4 b = *(const float4*)(centers + (size_t)m * 256 + k + 4);
        *(long*)(cfrag8 + (size_t)s * 8) = pack8_e4m3(a, b);
    } else {
        const int s = (bid - 384) * 256 + tid;               // 0..16383
        const int c = s >> 9, ct = (s >> 7) & 3, k2 = (s >> 6) & 1, lane = s & 63;
        const int o = ct * 32 + (lane & 31);
        const int m = c * 32 + k2 * 16 + (lane >> 5) * 8;
        const float4 a = *(const float4*)(W + (size_t)o * 1024 + m);
        const float4 b = *(const float4*)(W + (size_t)o * 1024 + m + 4);
        bf16x8 t;
        t[0]=f2bf(a.x); t[1]=f2bf(a.y); t[2]=f2bf(a.z); t[3]=f2bf(a.w);
        t[4]=f2bf(b.x); t[5]=f2bf(b.y); t[6]=f2bf(b.z); t[7]=f2bf(b.w);
        ((bf16x8*)wfrag)[s] = t;
    }
}

// ---------------- main: r4 geometry + intra-wave cross-pipe pipeline ----------------
// 512 blocks x 4 waves, 32 rows/wave, 32 chunks of 32 centers.
// Pipeline: iter c computes S(c) [fp8 MFMA, LDS A-frags] while executing
// exp/pack/PV of chunk c-1 [VALU + bf16 MFMA] from registers (Sp, wfp).
// Every carried value has a full chunk of latency slack. One barrier/chunk.
__global__ __launch_bounds__(256, 2) void rbf_main(
    const float* __restrict__ x, const float* __restrict__ bvec,
    const char* __restrict__ cfrag8, const short* __restrict__ wfrag,
    const float* __restrict__ ns, const float* __restrict__ nscs,
    const float* __restrict__ ts, float* __restrict__ out)
{
    __shared__ char  Cb8[2][8192];   // 8 KB/buf: 16 fp8 A-frags x 512B
    __shared__ short Wb[2][4096];    // 8 KB/buf: 8 bf16 B-frags x 1KB

    const int tid = threadIdx.x;
    const int lane = tid & 63;
    const int l31 = lane & 31;
    const int hi = lane >> 5;
    const int w = tid >> 6;
    const int qb = blockIdx.x * 128 + w * 32;

    // stage chunk `ci` into parity-P buffers (src per-lane, LDS dest wave-uniform)
#define STAGE(ci, P) do {                                                        \
        const char* _cs = cfrag8 + (size_t)(ci) * 8192 + w * 2048 + lane * 16;   \
        gload16(_cs,        &Cb8[(P)][w * 2048]);                                \
        gload16(_cs + 1024, &Cb8[(P)][w * 2048 + 1024]);                         \
        const char* _ws = (const char*)wfrag + (size_t)(ci) * 8192 + w * 2048 + lane * 16; \
        gload16(_ws,        (char*)&Wb[(P)][0] + w * 2048);                      \
        gload16(_ws + 1024, (char*)&Wb[(P)][0] + w * 2048 + 1024);               \
    } while (0)

    // ---- stage chunk 0 (DMA overlaps X prologue) ----
    STAGE(0, 0);

    // ---- X -> fp8 B-frags in regs + xs (fp32) ----
    long xq8[16];
    const float* xr = x + (size_t)(qb + l31) * 256 + hi * 8;
    float ss = 0.f;
    #pragma unroll
    for (int ks = 0; ks < 16; ++ks) {
        const float4 a = *(const float4*)(xr + ks * 16);
        const float4 b = *(const float4*)(xr + ks * 16 + 4);
        ss += a.x*a.x + a.y*a.y + a.z*a.z + a.w*a.w
            + b.x*b.x + b.y*b.y + b.z*b.z + b.w*b.w;
        xq8[ks] = pack8_e4m3(a, b);
    }
    ss += __shfl_xor(ss, 32, 64);
    const float xs = ss;

    f32x16 acc[4];
    #pragma unroll
    for (int ct = 0; ct < 4; ++ct) acc[ct] = zero16();

    __syncthreads();   // chunk 0 ready

    // ---- peeled iter 0: DMA(1), S(0), W(0) -> regs ----
    STAGE(1, 1);
    f32x16 Sp = zero16();
    {
        const char* cb = &Cb8[0][0] + (size_t)lane * 8;
        #pragma unroll
        for (int ks = 0; ks < 16; ++ks) {
            const long A = *(const long*)(cb + ks * 512);
            Sp = __builtin_amdgcn_mfma_f32_32x32x16_fp8_fp8(A, xq8[ks], Sp, 0, 0, 0);
        }
    }
    bf16x8 wfp[8];
    #pragma unroll
    for (int f = 0; f < 8; ++f) wfp[f] = ((const bf16x8*)&Wb[0][0])[f * 64 + lane];
    __syncthreads();   // chunk 1 ready

    for (int c = 1; c < 32; ++c) {
        const int P = c & 1;
        const int cn = (c < 31) ? c + 1 : 31;   // duplicate last DMA, harmless
        STAGE(cn, P ^ 1);

        // ---- S(c): fp8 MFMA chain, A-frags from LDS ----
        f32x16 S = zero16();
        {
            const char* cb = &Cb8[P][0] + (size_t)lane * 8;
            #pragma unroll
            for (int ks = 0; ks < 16; ++ks) {
                const long A = *(const long*)(cb + ks * 512);
                S = __builtin_amdgcn_mfma_f32_32x32x16_fp8_fp8(A, xq8[ks], S, 0, 0, 0);
            }
        }

        // ---- deferred exp/pack/PV for chunk c-1 (regs only: Sp, wfp) ----
        {
            const int cm = c - 1;
            float p[16];
            #pragma unroll
            for (int g4 = 0; g4 < 4; ++g4) {
                const float4 a4 = *(const float4*)(ns   + cm * 32 + g4 * 8 + hi * 4);
                const float4 b4 = *(const float4*)(nscs + cm * 32 + g4 * 8 + hi * 4);
                const float4 c4 = *(const float4*)(ts   + cm * 32 + g4 * 8 + hi * 4);
                const float* ap = (const float*)&a4;
                const float* bp = (const float*)&b4;
                const float* cp = (const float*)&c4;
                #pragma unroll
                for (int j = 0; j < 4; ++j) {
                    const float tt = fmaf(cp[j], Sp[g4 * 4 + j], fmaf(ap[j], xs, bp[j]));
                    p[g4 * 4 + j] = EXP2(tt);
                }
            }
            #pragma unroll
            for (int k2 = 0; k2 < 2; ++k2) {
                const int rb = k2 * 8;
                const u32 A = pack_bf16_trunc(p[rb + 0], p[rb + 1]);
                const u32 B = pack_bf16_trunc(p[rb + 2], p[rb + 3]);
                const u32 C = pack_bf16_trunc(p[rb + 4], p[rb + 5]);
                const u32 D = pack_bf16_trunc(p[rb + 6], p[rb + 7]);
                const u32 g0 = hi ? A : C;
                const u32 g1 = hi ? B : D;
                const u32 r0 = (u32)__shfl_xor((int)g0, 32, 64);
                const u32 r1 = (u32)__shfl_xor((int)g1, 32, 64);
                union { u32 u[4]; bf16x8 v; } pa;
                pa.u[0] = hi ? r0 : A;
                pa.u[1] = hi ? r1 : B;
                pa.u[2] = hi ? C : r0;
                pa.u[3] = hi ? D : r1;
                #pragma unroll
                for (int ct = 0; ct < 4; ++ct)
                    acc[ct] = __builtin_amdgcn_mfma_f32_32x32x16_bf16(pa.v, wfp[ct * 2 + k2], acc[ct], 0, 0, 0);
            }
        }

        // ---- W(c) -> regs for next iteration's PV ----
        bf16x8 wfc[8];
        #pragma unroll
        for (int f = 0; f < 8; ++f) wfc[f] = ((const bf16x8*)&Wb[P][0])[f * 64 + lane];

        __syncthreads();   // chunk c+1 DMA complete; all waves done with buf P
        Sp = S;
        #pragma unroll
        for (int f = 0; f < 8; ++f) wfp[f] = wfc[f];
    }

    // ---- drain: exp/pack/PV for chunk 31 ----
    {
        const int cm = 31;
        float p[16];
        #pragma unroll
        for (int g4 = 0; g4 < 4; ++g4) {
            const float4 a4 = *(const float4*)(ns   + cm * 32 + g4 * 8 + hi * 4);
            const float4 b4 = *(const float4*)(nscs + cm * 32 + g4 * 8 + hi * 4);
            const float4 c4 = *(const float4*)(ts   + cm * 32 + g4 * 8 + hi * 4);
            const float* ap = (const float*)&a4;
            const float* bp = (const float*)&b4;
            const float* cp = (const float*)&c4;
            #pragma unroll
            for (int j = 0; j < 4; ++j) {
                const float tt = fmaf(cp[j], Sp[g4 * 4 + j], fmaf(ap[j], xs, bp[j]));
                p[g4 * 4 + j] = EXP2(tt);
            }
        }
        #pragma unroll
        for (int k2 = 0; k2 < 2; ++k2) {
            const int rb = k2 * 8;
            const u32 A = pack_bf16_trunc(p[rb + 0], p[rb + 1]);
            const u32 B = pack_bf16_trunc(p[rb + 2], p[rb + 3]);
            const u32 C = pack_bf16_trunc(p[rb + 4], p[rb + 5]);
            const u32 D = pack_bf16_trunc(p[rb + 6], p[rb + 7]);
            const u32 g0 = hi ? A : C;
            const u32 g1 = hi ? B : D;
            const u32 r0 = (u32)__shfl_xor((int)g0, 32, 64);
            const u32 r1 = (u32)__shfl_xor((int)g1, 32, 64);
            union { u32 u[4]; bf16x8 v; } pa;
            pa.u[0] = hi ? r0 : A;
            pa.u[1] = hi ? r1 : B;
            pa.u[2] = hi ? C : r0;
            pa.u[3] = hi ? D : r1;
            #pragma unroll
            for (int ct = 0; ct < 4; ++ct)
                acc[ct] = __builtin_amdgcn_mfma_f32_32x32x16_bf16(pa.v, wfp[ct * 2 + k2], acc[ct], 0, 0, 0);
        }
    }

    // ---- epilogue: out[q][o] = acc + b ; D: col=l31 (o), row=(r&3)+8*(r>>2)+4*hi (q) ----
    float bq[4];
    #pragma unroll
    for (int ct = 0; ct < 4; ++ct) bq[ct] = bvec[ct * 32 + l31];
    #pragma unroll
    for (int r = 0; r < 16; ++r) {
        const int q = qb + (r & 3) + 8 * (r >> 2) + 4 * hi;
        #pragma unroll
        for (int ct = 0; ct < 4; ++ct)
            out[(size_t)q * 128 + ct * 32 + l31] = acc[ct][r] + bq[ct];
    }
#undef STAGE
}

extern "C" void kernel_launch(void* const* d_in, const int* in_sizes, int n_in,
                              void* d_out, int out_size, void* d_ws, size_t ws_size,
                              hipStream_t stream) {
    (void)in_sizes; (void)n_in; (void)out_size; (void)ws_size;
    const float* x       = (const float*)d_in[0];
    const float* centers = (const float*)d_in[1];
    const float* sigmas  = (const float*)d_in[2];
    const float* W       = (const float*)d_in[3];
    const float* b       = (const float*)d_in[4];
    float* out = (float*)d_out;

    char*  cfrag8 = (char*)d_ws;                     // 32768 slots * 8B  = 256 KB
    short* wfrag  = (short*)(cfrag8 + 32768 * 8);    // 16384 slots * 16B = 256 KB
    float* ns     = (float*)(wfrag + 16384 * 8);     // 4 KB
    float* nscs   = ns + 1024;                       // 4 KB
    float* ts     = nscs + 1024;                     // 4 KB

    rbf_prep<<<448, 256, 0, stream>>>(centers, sigmas, W, cfrag8, wfrag, ns, nscs, ts);
    rbf_main<<<512, 256, 0, stream>>>(x, b, cfrag8, wfrag, ns, nscs, ts, out);
}

// Round 9
// 83.575 us; speedup vs baseline: 5.9010x; 1.0638x over previous
//
#include <hip/hip_runtime.h>

typedef __attribute__((ext_vector_type(8))) short bf16x8;
typedef __attribute__((ext_vector_type(4))) float f32x4;
typedef unsigned int u32;
typedef unsigned long long u64;

#define LOG2E 1.44269504088896f

__device__ __forceinline__ short f2bf(float f) {
    union { float f; unsigned u; } v; v.f = f;
    unsigned r = v.u + 0x7fffu + ((v.u >> 16) & 1u);
    return (short)(r >> 16);
}

// float -> OCP e4m3fn byte (RNE, saturate to 448)
__device__ __forceinline__ u32 f2e4m3(float f) {
    u32 u = __float_as_uint(f);
    u32 sgn = (u >> 24) & 0x80u;
    u32 mag = u & 0x7fffffffu;
    if (mag >= 0x43E00000u) return sgn | 0x7Eu;
    if (mag < 0x3C800000u) {
        u32 q = (u32)(__uint_as_float(mag) * 512.0f + 0.5f);
        return sgn | q;
    }
    u32 r = mag + 0x0007FFFFu + ((mag >> 20) & 1u);
    u32 e8 = ((r >> 23) - 120u) & 0xFu;
    u32 m3 = (r >> 20) & 7u;
    return sgn | (e8 << 3) | m3;
}

__device__ __forceinline__ long pack8_e4m3(float4 a, float4 b) {
    u32 lo = f2e4m3(a.x) | (f2e4m3(a.y) << 8) | (f2e4m3(a.z) << 16) | (f2e4m3(a.w) << 24);
    u32 hi = f2e4m3(b.x) | (f2e4m3(b.y) << 8) | (f2e4m3(b.z) << 16) | (f2e4m3(b.w) << 24);
    return (long)(((u64)hi << 32) | lo);
}

#if __has_builtin(__builtin_amdgcn_exp2f)
#define EXP2(x) __builtin_amdgcn_exp2f(x)
#else
#define EXP2(x) __builtin_exp2f(x)
#endif

__device__ __forceinline__ u32 pack_bf16_trunc(float lo, float hi) {
#if __has_builtin(__builtin_amdgcn_perm)
    return __builtin_amdgcn_perm(__float_as_uint(hi), __float_as_uint(lo), 0x07060302u);
#else
    return (__float_as_uint(hi) & 0xFFFF0000u) | (__float_as_uint(lo) >> 16);
#endif
}

__device__ __forceinline__ void gload16(const void* g, void* l) {
    __builtin_amdgcn_global_load_lds(
        (const __attribute__((address_space(1))) void*)g,
        (__attribute__((address_space(3))) void*)l, 16, 0, 0);
}

// ---------------- prep ----------------
// Center permutation (zero-shuffle S->PV): S-mfma half h, lane-group g=(l>>4),
// reg j covers ACTUAL center  m = c*32 + 8g + 4h + j.  Then PV A-frag element
// jj (0..7) at group g is actual center 8g+jj == mfma K-index -> W needs no perm.
//
// blocks 0..255  : per-center scalars into PERMUTED tables (4 rows/block):
//                  row m -> slot ((c*2+h)*4+g)*4+j, values: ns=-s*L, nscs=-s*||c||^2*L, ts=2s*L
// blocks 256..383: centers -> cfrag8 (fp8), A-frag: slot s=[c][h][ks][lane] 8B:
//                  center m(c,h,l15) = c*32+8*(l15>>2)+4*h+(l15&3), k = ks*32+(l>>4)*8
// blocks 384..447: W -> wfrag (bf16) PV B-frag: slot s=[c][ot][lane] 16B:
//                  o = ot*16+(l&15), k = c*32+(l>>4)*8
__global__ __launch_bounds__(256) void rbf_prep(
    const float* __restrict__ centers, const float* __restrict__ sigmas,
    const float* __restrict__ W,
    char* __restrict__ cfrag8, short* __restrict__ wfrag,
    float* __restrict__ nsp, float* __restrict__ nscsp, float* __restrict__ tsp)
{
    const int tid = threadIdx.x;
    const int bid = blockIdx.x;
    if (bid < 256) {
        const int lane = tid & 63, w = tid >> 6;
        const int m = bid * 4 + w;
        const float4 v = ((const float4*)(centers + (size_t)m * 256))[lane];
        float s = v.x*v.x + v.y*v.y + v.z*v.z + v.w*v.w;
        #pragma unroll
        for (int off = 32; off >= 1; off >>= 1) s += __shfl_xor(s, off, 64);
        if (lane == 0) {
            const float sg = sigmas[m];
            const int c = m >> 5, w5 = m & 31;
            const int g = w5 >> 3, r = w5 & 7, h = r >> 2, j = r & 3;
            const int slot = ((c * 2 + h) * 4 + g) * 4 + j;
            nsp[slot]   = -sg * LOG2E;
            nscsp[slot] = -sg * s * LOG2E;
            tsp[slot]   = 2.0f * sg * LOG2E;
        }
    } else if (bid < 384) {
        const int s = (bid - 256) * 256 + tid;               // 0..32767
        const int c = s >> 10, h = (s >> 9) & 1, ks = (s >> 6) & 7, lane = s & 63;
        const int l15 = lane & 15;
        const int m = c * 32 + 8 * (l15 >> 2) + 4 * h + (l15 & 3);
        const int k = ks * 32 + (lane >> 4) * 8;
        const float4 a = *(const float4*)(centers + (size_t)m * 256 + k);
        const float4 b = *(const float4*)(centers + (size_t)m * 256 + k + 4);
        *(long*)(cfrag8 + (size_t)s * 8) = pack8_e4m3(a, b);
    } else {
        const int s = (bid - 384) * 256 + tid;               // 0..16383
        const int c = s >> 9, ot = (s >> 6) & 7, lane = s & 63;
        const int o = ot * 16 + (lane & 15);
        const int k = c * 32 + (lane >> 4) * 8;
        const float4 a = *(const float4*)(W + (size_t)o * 1024 + k);
        const float4 b = *(const float4*)(W + (size_t)o * 1024 + k + 4);
        bf16x8 t;
        t[0]=f2bf(a.x); t[1]=f2bf(a.y); t[2]=f2bf(a.z); t[3]=f2bf(a.w);
        t[4]=f2bf(b.x); t[5]=f2bf(b.y); t[6]=f2bf(b.z); t[7]=f2bf(b.w);
        ((bf16x8*)wfrag)[s] = t;
    }
}

// ---------------- main: 16 rows/wave, 16x16x32 MFMA, 4 waves/SIMD ----------------
// 1024 blocks x 4 waves = 4 blocks/CU, 16 waves/CU. Per chunk (32 centers):
// DMA(next) -> S (2 fp8 mfma-halves x 8 k-steps) -> exp (zero-shuffle pack) ->
// PV (8 bf16 mfma, W from LDS) -> barrier. LDS 32 KB/block.
__global__ __launch_bounds__(256, 4) void rbf_main(
    const float* __restrict__ x, const float* __restrict__ bvec,
    const char* __restrict__ cfrag8, const short* __restrict__ wfrag,
    const float* __restrict__ nsp, const float* __restrict__ nscsp,
    const float* __restrict__ tsp, float* __restrict__ out)
{
    __shared__ char  Cb8[2][8192];   // [h][ks][lane]: h*4096 + ks*512 + lane*8
    __shared__ short Wb[2][4096];    // [ot][lane]: ot*1024B + lane*16B

    const int tid = threadIdx.x;
    const int lane = tid & 63;
    const int l15 = lane & 15;
    const int g4 = lane >> 4;       // 0..3
    const int w = tid >> 6;
    const int qb = blockIdx.x * 64 + w * 16;

#define STAGE(ci, P) do {                                                         \
        const char* _cs = cfrag8 + (size_t)(ci) * 8192 + w * 2048 + lane * 16;    \
        gload16(_cs,        &Cb8[(P)][w * 2048]);                                 \
        gload16(_cs + 1024, &Cb8[(P)][w * 2048 + 1024]);                          \
        const char* _ws = (const char*)wfrag + (size_t)(ci) * 8192 + w * 2048 + lane * 16; \
        gload16(_ws,        (char*)&Wb[(P)][0] + w * 2048);                       \
        gload16(_ws + 1024, (char*)&Wb[(P)][0] + w * 2048 + 1024);                \
    } while (0)

    // ---- stage chunk 0 (DMA overlaps X prologue) ----
    STAGE(0, 0);

    // ---- X -> fp8 B-frags (lane: q=qb+l15, k=ks*32+g4*8+j) + xs ----
    long xq8[8];
    const float* xr = x + (size_t)(qb + l15) * 256 + g4 * 8;
    float ss = 0.f;
    #pragma unroll
    for (int ks = 0; ks < 8; ++ks) {
        const float4 a = *(const float4*)(xr + ks * 32);
        const float4 b = *(const float4*)(xr + ks * 32 + 4);
        ss += a.x*a.x + a.y*a.y + a.z*a.z + a.w*a.w
            + b.x*b.x + b.y*b.y + b.z*b.z + b.w*b.w;
        xq8[ks] = pack8_e4m3(a, b);
    }
    ss += __shfl_xor(ss, 16, 64);
    ss += __shfl_xor(ss, 32, 64);
    const float xs = ss;            // full ||x_q||^2 for q = qb + l15

    f32x4 acc[8];
    #pragma unroll
    for (int ot = 0; ot < 8; ++ot) acc[ot] = (f32x4){0.f, 0.f, 0.f, 0.f};

    __syncthreads();   // chunk 0 DMA complete (compiler-inserted vmcnt before barrier)

    int buf = 0;
    for (int c = 0; c < 32; ++c) {
        const int cn = (c < 31) ? c + 1 : 31;   // redundant last stage, harmless
        STAGE(cn, buf ^ 1);

        // ---- S: 2 half-chunks x 8 k-steps of fp8 16x16x32 ----
        // D: lane holds S[m-quad j][q=l15], actual center = c*32 + 8*g4 + 4*h + j
        f32x4 s0 = (f32x4){0.f,0.f,0.f,0.f}, s1 = (f32x4){0.f,0.f,0.f,0.f};
        {
            const char* cb = &Cb8[buf][0] + (size_t)lane * 8;
            #pragma unroll
            for (int ks = 0; ks < 8; ++ks) {
                const long A0 = *(const long*)(cb + ks * 512);
                const long A1 = *(const long*)(cb + 4096 + ks * 512);
                s0 = __builtin_amdgcn_mfma_f32_16x16x32_fp8_fp8(A0, xq8[ks], s0, 0, 0, 0);
                s1 = __builtin_amdgcn_mfma_f32_16x16x32_fp8_fp8(A1, xq8[ks], s1, 0, 0, 0);
            }
        }

        // ---- phi = exp2(ts*S + ns*xs + nscs), permuted tables, zero-shuffle ----
        float p0[4], p1[4];
        {
            const int base0 = (c * 2 + 0) * 4 + g4;
            const int base1 = (c * 2 + 1) * 4 + g4;
            const float4 n0 = ((const float4*)nsp)[base0];
            const float4 q0 = ((const float4*)nscsp)[base0];
            const float4 t0 = ((const float4*)tsp)[base0];
            const float4 n1 = ((const float4*)nsp)[base1];
            const float4 q1 = ((const float4*)nscsp)[base1];
            const float4 t1 = ((const float4*)tsp)[base1];
            const float* n0p = (const float*)&n0; const float* q0p = (const float*)&q0;
            const float* t0p = (const float*)&t0; const float* n1p = (const float*)&n1;
            const float* q1p = (const float*)&q1; const float* t1p = (const float*)&t1;
            #pragma unroll
            for (int j = 0; j < 4; ++j) {
                p0[j] = EXP2(fmaf(t0p[j], s0[j], fmaf(n0p[j], xs, q0p[j])));
                p1[j] = EXP2(fmaf(t1p[j], s1[j], fmaf(n1p[j], xs, q1p[j])));
            }
        }
        union { u32 u[4]; bf16x8 v; } pa;
        pa.u[0] = pack_bf16_trunc(p0[0], p0[1]);
        pa.u[1] = pack_bf16_trunc(p0[2], p0[3]);
        pa.u[2] = pack_bf16_trunc(p1[0], p1[1]);
        pa.u[3] = pack_bf16_trunc(p1[2], p1[3]);
        // A-frag element jj at group g4 = actual center 8*g4 + jj == PV K-index ✓

        // ---- PV: out[q][o] += phi @ W^T, 8 bf16 16x16x32, B from LDS ----
        {
            const bf16x8* wbl = (const bf16x8*)&Wb[buf][0] + lane;
            #pragma unroll
            for (int ot = 0; ot < 8; ++ot)
                acc[ot] = __builtin_amdgcn_mfma_f32_16x16x32_bf16(pa.v, wbl[ot * 64], acc[ot], 0, 0, 0);
        }

        __syncthreads();   // next chunk's DMA landed; all waves done with buf
        buf ^= 1;
    }

    // ---- epilogue: D layout col=l15 (o-sub), row=g4*4+jr (q-sub) ----
    #pragma unroll
    for (int jr = 0; jr < 4; ++jr) {
        const int q = qb + g4 * 4 + jr;
        #pragma unroll
        for (int ot = 0; ot < 8; ++ot)
            out[(size_t)q * 128 + ot * 16 + l15] = acc[ot][jr] + bvec[ot * 16 + l15];
    }
#undef STAGE
}

extern "C" void kernel_launch(void* const* d_in, const int* in_sizes, int n_in,
                              void* d_out, int out_size, void* d_ws, size_t ws_size,
                              hipStream_t stream) {
    (void)in_sizes; (void)n_in; (void)out_size; (void)ws_size;
    const float* x       = (const float*)d_in[0];
    const float* centers = (const float*)d_in[1];
    const float* sigmas  = (const float*)d_in[2];
    const float* W       = (const float*)d_in[3];
    const float* b       = (const float*)d_in[4];
    float* out = (float*)d_out;

    char*  cfrag8 = (char*)d_ws;                     // 32768 slots * 8B  = 256 KB
    short* wfrag  = (short*)(cfrag8 + 32768 * 8);    // 16384 slots * 16B = 256 KB
    float* nsp    = (float*)(wfrag + 16384 * 8);     // 4 KB
    float* nscsp  = nsp + 1024;                      // 4 KB
    float* tsp    = nscsp + 1024;                    // 4 KB

    rbf_prep<<<448, 256, 0, stream>>>(centers, sigmas, W, cfrag8, wfrag, nsp, nscsp, tsp);
    rbf_main<<<1024, 256, 0, stream>>>(x, b, cfrag8, wfrag, nsp, nscsp, tsp, out);
}

// Round 10
// 82.148 us; speedup vs baseline: 6.0035x; 1.0174x over previous
//
#include <hip/hip_runtime.h>

typedef __attribute__((ext_vector_type(8))) short bf16x8;
typedef __attribute__((ext_vector_type(4))) float f32x4;
typedef unsigned int u32;
typedef unsigned long long u64;

#define LOG2E 1.44269504088896f

__device__ __forceinline__ short f2bf(float f) {
    union { float f; unsigned u; } v; v.f = f;
    unsigned r = v.u + 0x7fffu + ((v.u >> 16) & 1u);
    return (short)(r >> 16);
}

// float -> OCP e4m3fn byte (RNE, saturate to 448)
__device__ __forceinline__ u32 f2e4m3(float f) {
    u32 u = __float_as_uint(f);
    u32 sgn = (u >> 24) & 0x80u;
    u32 mag = u & 0x7fffffffu;
    if (mag >= 0x43E00000u) return sgn | 0x7Eu;
    if (mag < 0x3C800000u) {
        u32 q = (u32)(__uint_as_float(mag) * 512.0f + 0.5f);
        return sgn | q;
    }
    u32 r = mag + 0x0007FFFFu + ((mag >> 20) & 1u);
    u32 e8 = ((r >> 23) - 120u) & 0xFu;
    u32 m3 = (r >> 20) & 7u;
    return sgn | (e8 << 3) | m3;
}

__device__ __forceinline__ long pack8_e4m3(float4 a, float4 b) {
    u32 lo = f2e4m3(a.x) | (f2e4m3(a.y) << 8) | (f2e4m3(a.z) << 16) | (f2e4m3(a.w) << 24);
    u32 hi = f2e4m3(b.x) | (f2e4m3(b.y) << 8) | (f2e4m3(b.z) << 16) | (f2e4m3(b.w) << 24);
    return (long)(((u64)hi << 32) | lo);
}

#if __has_builtin(__builtin_amdgcn_exp2f)
#define EXP2(x) __builtin_amdgcn_exp2f(x)
#else
#define EXP2(x) __builtin_exp2f(x)
#endif

__device__ __forceinline__ u32 pack_bf16_trunc(float lo, float hi) {
#if __has_builtin(__builtin_amdgcn_perm)
    return __builtin_amdgcn_perm(__float_as_uint(hi), __float_as_uint(lo), 0x07060302u);
#else
    return (__float_as_uint(hi) & 0xFFFF0000u) | (__float_as_uint(lo) >> 16);
#endif
}

__device__ __forceinline__ void gload16(const void* g, void* l) {
    __builtin_amdgcn_global_load_lds(
        (const __attribute__((address_space(1))) void*)g,
        (__attribute__((address_space(3))) void*)l, 16, 0, 0);
}

// ---------------- prep (verbatim from round 9; absmax 0.0 verified) ----------------
// blocks 0..255  : per-center scalars into PERMUTED tables: m -> slot ((c*2+h)*4+g)*4+j
// blocks 256..383: centers -> cfrag8 (fp8), A-frag: slot s=[c][h][ks][lane] 8B:
//                  center m(c,h,l15) = c*32+8*(l15>>2)+4*h+(l15&3), k = ks*32+(l>>4)*8
// blocks 384..447: W -> wfrag (bf16) PV B-frag: slot s=[c][ot][lane] 16B:
//                  o = ot*16+(l&15), k = c*32+(l>>4)*8
__global__ __launch_bounds__(256) void rbf_prep(
    const float* __restrict__ centers, const float* __restrict__ sigmas,
    const float* __restrict__ W,
    char* __restrict__ cfrag8, short* __restrict__ wfrag,
    float* __restrict__ nsp, float* __restrict__ nscsp, float* __restrict__ tsp)
{
    const int tid = threadIdx.x;
    const int bid = blockIdx.x;
    if (bid < 256) {
        const int lane = tid & 63, w = tid >> 6;
        const int m = bid * 4 + w;
        const float4 v = ((const float4*)(centers + (size_t)m * 256))[lane];
        float s = v.x*v.x + v.y*v.y + v.z*v.z + v.w*v.w;
        #pragma unroll
        for (int off = 32; off >= 1; off >>= 1) s += __shfl_xor(s, off, 64);
        if (lane == 0) {
            const float sg = sigmas[m];
            const int c = m >> 5, w5 = m & 31;
            const int g = w5 >> 3, r = w5 & 7, h = r >> 2, j = r & 3;
            const int slot = ((c * 2 + h) * 4 + g) * 4 + j;
            nsp[slot]   = -sg * LOG2E;
            nscsp[slot] = -sg * s * LOG2E;
            tsp[slot]   = 2.0f * sg * LOG2E;
        }
    } else if (bid < 384) {
        const int s = (bid - 256) * 256 + tid;               // 0..32767
        const int c = s >> 10, h = (s >> 9) & 1, ks = (s >> 6) & 7, lane = s & 63;
        const int l15 = lane & 15;
        const int m = c * 32 + 8 * (l15 >> 2) + 4 * h + (l15 & 3);
        const int k = ks * 32 + (lane >> 4) * 8;
        const float4 a = *(const float4*)(centers + (size_t)m * 256 + k);
        const float4 b = *(const float4*)(centers + (size_t)m * 256 + k + 4);
        *(long*)(cfrag8 + (size_t)s * 8) = pack8_e4m3(a, b);
    } else {
        const int s = (bid - 384) * 256 + tid;               // 0..16383
        const int c = s >> 9, ot = (s >> 6) & 7, lane = s & 63;
        const int o = ot * 16 + (lane & 15);
        const int k = c * 32 + (lane >> 4) * 8;
        const float4 a = *(const float4*)(W + (size_t)o * 1024 + k);
        const float4 b = *(const float4*)(W + (size_t)o * 1024 + k + 4);
        bf16x8 t;
        t[0]=f2bf(a.x); t[1]=f2bf(a.y); t[2]=f2bf(a.z); t[3]=f2bf(a.w);
        t[4]=f2bf(b.x); t[5]=f2bf(b.y); t[6]=f2bf(b.z); t[7]=f2bf(b.w);
        ((bf16x8*)wfrag)[s] = t;
    }
}

// ---------------- main: T3+T4 — 4-deep ring, counted vmcnt, raw barrier ----------------
// 256 blocks x 512 threads (8 waves, 2/SIMD, 1 block/CU). Wave owns 32 rows as
// two 16-row tiles; every C/W LDS read feeds BOTH tiles (2x reuse). Per iter:
// STAGE(c+3) -> S (fp8, 4 indep chains) -> exp/pack (zero-shuffle) -> PV (bf16)
// -> s_waitcnt vmcnt(4) [counted, never 0 mid-loop] -> raw s_barrier.
__global__ __launch_bounds__(512, 2) void rbf_main(
    const float* __restrict__ x, const float* __restrict__ bvec,
    const char* __restrict__ cfrag8, const short* __restrict__ wfrag,
    const float* __restrict__ nsp, const float* __restrict__ nscsp,
    const float* __restrict__ tsp, float* __restrict__ out)
{
    __shared__ char  Cb8[4][8192];   // ring: [h][ks][lane] = h*4096 + ks*512 + lane*8
    __shared__ short Wb[4][4096];    // ring: [ot][lane]    = ot*1024B + lane*16B

    const int tid = threadIdx.x;
    const int lane = tid & 63;
    const int l15 = lane & 15;
    const int g4 = lane >> 4;
    const int w = tid >> 6;                    // 0..7
    const int qb = blockIdx.x * 256 + w * 32;  // 32 rows per wave

    // per STAGE: 2 gload16 per wave (1 KB of C + 1 KB of W)
#define STAGE(ci, slot) do {                                                       \
        const char* _cs = cfrag8 + (size_t)(ci) * 8192 + w * 1024 + lane * 16;     \
        gload16(_cs, &Cb8[(slot)][w * 1024]);                                      \
        const char* _ws = (const char*)wfrag + (size_t)(ci) * 8192 + w * 1024 + lane * 16; \
        gload16(_ws, (char*)&Wb[(slot)][0] + w * 1024);                            \
    } while (0)

    // ---- prologue: stage chunks 0..2 (DMA lands under the X prologue) ----
    STAGE(0, 0);
    STAGE(1, 1);
    STAGE(2, 2);

    // ---- X -> fp8 B-frags for two tiles + xs ----
    long xq8[2][8];
    float xs[2];
    #pragma unroll
    for (int t = 0; t < 2; ++t) {
        const float* xr = x + (size_t)(qb + t * 16 + l15) * 256 + g4 * 8;
        float ss = 0.f;
        #pragma unroll
        for (int ks = 0; ks < 8; ++ks) {
            const float4 a = *(const float4*)(xr + ks * 32);
            const float4 b = *(const float4*)(xr + ks * 32 + 4);
            ss += a.x*a.x + a.y*a.y + a.z*a.z + a.w*a.w
                + b.x*b.x + b.y*b.y + b.z*b.z + b.w*b.w;
            xq8[t][ks] = pack8_e4m3(a, b);
        }
        ss += __shfl_xor(ss, 16, 64);
        ss += __shfl_xor(ss, 32, 64);
        xs[t] = ss;
    }

    f32x4 acc[2][8];
    #pragma unroll
    for (int t = 0; t < 2; ++t)
        #pragma unroll
        for (int ot = 0; ot < 8; ++ot) acc[t][ot] = (f32x4){0.f, 0.f, 0.f, 0.f};

    asm volatile("s_waitcnt vmcnt(0)" ::: "memory");   // prologue-only full drain
    __builtin_amdgcn_s_barrier();

    for (int c = 0; c < 32; ++c) {
        const int slot = c & 3;
        if (c < 29) STAGE(c + 3, (c + 3) & 3);

        // ---- S: 8 k-steps x {2 halves x 2 tiles} fp8 MFMA (A shared across tiles) ----
        f32x4 s00 = (f32x4){0.f,0.f,0.f,0.f}, s01 = s00, s10 = s00, s11 = s00;
        {
            const char* cb = &Cb8[slot][0] + (size_t)lane * 8;
            __builtin_amdgcn_s_setprio(1);
            #pragma unroll
            for (int ks = 0; ks < 8; ++ks) {
                const long A0 = *(const long*)(cb + ks * 512);
                const long A1 = *(const long*)(cb + 4096 + ks * 512);
                s00 = __builtin_amdgcn_mfma_f32_16x16x32_fp8_fp8(A0, xq8[0][ks], s00, 0, 0, 0);
                s10 = __builtin_amdgcn_mfma_f32_16x16x32_fp8_fp8(A0, xq8[1][ks], s10, 0, 0, 0);
                s01 = __builtin_amdgcn_mfma_f32_16x16x32_fp8_fp8(A1, xq8[0][ks], s01, 0, 0, 0);
                s11 = __builtin_amdgcn_mfma_f32_16x16x32_fp8_fp8(A1, xq8[1][ks], s11, 0, 0, 0);
            }
            __builtin_amdgcn_s_setprio(0);
        }

        // ---- phi = exp2(ts*S + ns*xs + nscs); tables shared by both tiles ----
        const int base0 = (c * 2 + 0) * 4 + g4;
        const int base1 = (c * 2 + 1) * 4 + g4;
        const float4 n0 = ((const float4*)nsp)[base0];
        const float4 q0 = ((const float4*)nscsp)[base0];
        const float4 t0 = ((const float4*)tsp)[base0];
        const float4 n1 = ((const float4*)nsp)[base1];
        const float4 q1 = ((const float4*)nscsp)[base1];
        const float4 t1 = ((const float4*)tsp)[base1];
        const float* n0p = (const float*)&n0; const float* q0p = (const float*)&q0;
        const float* t0p = (const float*)&t0; const float* n1p = (const float*)&n1;
        const float* q1p = (const float*)&q1; const float* t1p = (const float*)&t1;

        union { u32 u[4]; bf16x8 v; } pa0, pa1;
        {
            float p00[4], p01[4], p10[4], p11[4];
            #pragma unroll
            for (int j = 0; j < 4; ++j) {
                p00[j] = EXP2(fmaf(t0p[j], s00[j], fmaf(n0p[j], xs[0], q0p[j])));
                p01[j] = EXP2(fmaf(t1p[j], s01[j], fmaf(n1p[j], xs[0], q1p[j])));
                p10[j] = EXP2(fmaf(t0p[j], s10[j], fmaf(n0p[j], xs[1], q0p[j])));
                p11[j] = EXP2(fmaf(t1p[j], s11[j], fmaf(n1p[j], xs[1], q1p[j])));
            }
            pa0.u[0] = pack_bf16_trunc(p00[0], p00[1]);
            pa0.u[1] = pack_bf16_trunc(p00[2], p00[3]);
            pa0.u[2] = pack_bf16_trunc(p01[0], p01[1]);
            pa0.u[3] = pack_bf16_trunc(p01[2], p01[3]);
            pa1.u[0] = pack_bf16_trunc(p10[0], p10[1]);
            pa1.u[1] = pack_bf16_trunc(p10[2], p10[3]);
            pa1.u[2] = pack_bf16_trunc(p11[0], p11[1]);
            pa1.u[3] = pack_bf16_trunc(p11[2], p11[3]);
        }

        // ---- PV: 8 W-frag reads feed 16 bf16 MFMAs (W shared across tiles) ----
        {
            const bf16x8* wbl = (const bf16x8*)&Wb[slot][0] + lane;
            __builtin_amdgcn_s_setprio(1);
            #pragma unroll
            for (int ot = 0; ot < 8; ++ot) {
                const bf16x8 wv = wbl[ot * 64];
                acc[0][ot] = __builtin_amdgcn_mfma_f32_16x16x32_bf16(pa0.v, wv, acc[0][ot], 0, 0, 0);
                acc[1][ot] = __builtin_amdgcn_mfma_f32_16x16x32_bf16(pa1.v, wv, acc[1][ot], 0, 0, 0);
            }
            __builtin_amdgcn_s_setprio(0);
        }

        // ---- counted wait (T4): chunk c+1's loads landed; c+2,c+3 stay in flight ----
        if (c < 29)       asm volatile("s_waitcnt vmcnt(4)" ::: "memory");
        else if (c == 29) asm volatile("s_waitcnt vmcnt(2)" ::: "memory");
        else if (c == 30) asm volatile("s_waitcnt vmcnt(0)" ::: "memory");
        if (c < 31) __builtin_amdgcn_s_barrier();
    }

    // ---- epilogue: D layout col=l15 (o-sub), row=g4*4+jr (q-sub) ----
    #pragma unroll
    for (int t = 0; t < 2; ++t) {
        #pragma unroll
        for (int jr = 0; jr < 4; ++jr) {
            const int q = qb + t * 16 + g4 * 4 + jr;
            #pragma unroll
            for (int ot = 0; ot < 8; ++ot)
                out[(size_t)q * 128 + ot * 16 + l15] = acc[t][ot][jr] + bvec[ot * 16 + l15];
        }
    }
#undef STAGE
}

extern "C" void kernel_launch(void* const* d_in, const int* in_sizes, int n_in,
                              void* d_out, int out_size, void* d_ws, size_t ws_size,
                              hipStream_t stream) {
    (void)in_sizes; (void)n_in; (void)out_size; (void)ws_size;
    const float* x       = (const float*)d_in[0];
    const float* centers = (const float*)d_in[1];
    const float* sigmas  = (const float*)d_in[2];
    const float* W       = (const float*)d_in[3];
    const float* b       = (const float*)d_in[4];
    float* out = (float*)d_out;

    char*  cfrag8 = (char*)d_ws;                     // 32768 slots * 8B  = 256 KB
    short* wfrag  = (short*)(cfrag8 + 32768 * 8);    // 16384 slots * 16B = 256 KB
    float* nsp    = (float*)(wfrag + 16384 * 8);     // 4 KB
    float* nscsp  = nsp + 1024;                      // 4 KB
    float* tsp    = nscsp + 1024;                    // 4 KB

    rbf_prep<<<448, 256, 0, stream>>>(centers, sigmas, W, cfrag8, wfrag, nsp, nscsp, tsp);
    rbf_main<<<256, 512, 0, stream>>>(x, b, cfrag8, wfrag, nsp, nscsp, tsp, out);
}

// Round 11
// 71.245 us; speedup vs baseline: 6.9222x; 1.1530x over previous
//
#include <hip/hip_runtime.h>

typedef __attribute__((ext_vector_type(8))) short bf16x8;
typedef __attribute__((ext_vector_type(4))) float f32x4;
typedef unsigned int u32;
typedef unsigned long long u64;

#define LOG2E 1.44269504088896f

__device__ __forceinline__ short f2bf(float f) {
    union { float f; unsigned u; } v; v.f = f;
    unsigned r = v.u + 0x7fffu + ((v.u >> 16) & 1u);
    return (short)(r >> 16);
}

// float -> OCP e4m3fn byte (RNE, saturate to 448)
__device__ __forceinline__ u32 f2e4m3(float f) {
    u32 u = __float_as_uint(f);
    u32 sgn = (u >> 24) & 0x80u;
    u32 mag = u & 0x7fffffffu;
    if (mag >= 0x43E00000u) return sgn | 0x7Eu;
    if (mag < 0x3C800000u) {
        u32 q = (u32)(__uint_as_float(mag) * 512.0f + 0.5f);
        return sgn | q;
    }
    u32 r = mag + 0x0007FFFFu + ((mag >> 20) & 1u);
    u32 e8 = ((r >> 23) - 120u) & 0xFu;
    u32 m3 = (r >> 20) & 7u;
    return sgn | (e8 << 3) | m3;
}

__device__ __forceinline__ long pack8_e4m3(float4 a, float4 b) {
    u32 lo = f2e4m3(a.x) | (f2e4m3(a.y) << 8) | (f2e4m3(a.z) << 16) | (f2e4m3(a.w) << 24);
    u32 hi = f2e4m3(b.x) | (f2e4m3(b.y) << 8) | (f2e4m3(b.z) << 16) | (f2e4m3(b.w) << 24);
    return (long)(((u64)hi << 32) | lo);
}

#if __has_builtin(__builtin_amdgcn_exp2f)
#define EXP2(x) __builtin_amdgcn_exp2f(x)
#else
#define EXP2(x) __builtin_exp2f(x)
#endif

__device__ __forceinline__ u32 pack_bf16_trunc(float lo, float hi) {
#if __has_builtin(__builtin_amdgcn_perm)
    return __builtin_amdgcn_perm(__float_as_uint(hi), __float_as_uint(lo), 0x07060302u);
#else
    return (__float_as_uint(hi) & 0xFFFF0000u) | (__float_as_uint(lo) >> 16);
#endif
}

__device__ __forceinline__ void gload16(const void* g, void* l) {
    __builtin_amdgcn_global_load_lds(
        (const __attribute__((address_space(1))) void*)g,
        (__attribute__((address_space(3))) void*)l, 16, 0, 0);
}

// ---------------- prep (verbatim from round 9; absmax 0.0 verified) ----------------
// blocks 0..255  : per-center scalars into PERMUTED tables: m -> slot ((c*2+h)*4+g)*4+j
// blocks 256..383: centers -> cfrag8 (fp8), A-frag: slot s=[c][h][ks][lane] 8B:
//                  center m(c,h,l15) = c*32+8*(l15>>2)+4*h+(l15&3), k = ks*32+(l>>4)*8
// blocks 384..447: W -> wfrag (bf16) PV B-frag: slot s=[c][ot][lane] 16B:
//                  o = ot*16+(l&15), k = c*32+(l>>4)*8
__global__ __launch_bounds__(256) void rbf_prep(
    const float* __restrict__ centers, const float* __restrict__ sigmas,
    const float* __restrict__ W,
    char* __restrict__ cfrag8, short* __restrict__ wfrag,
    float* __restrict__ nsp, float* __restrict__ nscsp, float* __restrict__ tsp)
{
    const int tid = threadIdx.x;
    const int bid = blockIdx.x;
    if (bid < 256) {
        const int lane = tid & 63, w = tid >> 6;
        const int m = bid * 4 + w;
        const float4 v = ((const float4*)(centers + (size_t)m * 256))[lane];
        float s = v.x*v.x + v.y*v.y + v.z*v.z + v.w*v.w;
        #pragma unroll
        for (int off = 32; off >= 1; off >>= 1) s += __shfl_xor(s, off, 64);
        if (lane == 0) {
            const float sg = sigmas[m];
            const int c = m >> 5, w5 = m & 31;
            const int g = w5 >> 3, r = w5 & 7, h = r >> 2, j = r & 3;
            const int slot = ((c * 2 + h) * 4 + g) * 4 + j;
            nsp[slot]   = -sg * LOG2E;
            nscsp[slot] = -sg * s * LOG2E;
            tsp[slot]   = 2.0f * sg * LOG2E;
        }
    } else if (bid < 384) {
        const int s = (bid - 256) * 256 + tid;               // 0..32767
        const int c = s >> 10, h = (s >> 9) & 1, ks = (s >> 6) & 7, lane = s & 63;
        const int l15 = lane & 15;
        const int m = c * 32 + 8 * (l15 >> 2) + 4 * h + (l15 & 3);
        const int k = ks * 32 + (lane >> 4) * 8;
        const float4 a = *(const float4*)(centers + (size_t)m * 256 + k);
        const float4 b = *(const float4*)(centers + (size_t)m * 256 + k + 4);
        *(long*)(cfrag8 + (size_t)s * 8) = pack8_e4m3(a, b);
    } else {
        const int s = (bid - 384) * 256 + tid;               // 0..16383
        const int c = s >> 9, ot = (s >> 6) & 7, lane = s & 63;
        const int o = ot * 16 + (lane & 15);
        const int k = c * 32 + (lane >> 4) * 8;
        const float4 a = *(const float4*)(W + (size_t)o * 1024 + k);
        const float4 b = *(const float4*)(W + (size_t)o * 1024 + k + 4);
        bf16x8 t;
        t[0]=f2bf(a.x); t[1]=f2bf(a.y); t[2]=f2bf(a.z); t[3]=f2bf(a.w);
        t[4]=f2bf(b.x); t[5]=f2bf(b.y); t[6]=f2bf(b.z); t[7]=f2bf(b.w);
        ((bf16x8*)wfrag)[s] = t;
    }
}

// ---------------- main: r10 pipeline with a CLEAN vmcnt domain ----------------
// 512 blocks x 256 threads (4 waves), 2 blocks/CU. Tables live in LDS (loaded
// once in the prologue), so the chunk loop's ONLY vmem ops are the STAGE DMAs:
// no compiler-inserted vmcnt wait can drain the ring (in-order vmcnt retirement
// made the r3-r10 table loads force-drain every chunk's staging). Ring depth 4,
// counted vmcnt(8/4/0), raw s_barrier.
__global__ __launch_bounds__(256, 2) void rbf_main(
    const float* __restrict__ x, const float* __restrict__ bvec,
    const char* __restrict__ cfrag8, const short* __restrict__ wfrag,
    const float* __restrict__ nsp, const float* __restrict__ nscsp,
    const float* __restrict__ tsp, float* __restrict__ out)
{
    __shared__ char  Cb8[4][8192];   // ring: [h][ks][lane] = h*4096 + ks*512 + lane*8
    __shared__ short Wb[4][4096];    // ring: [ot][lane]    = ot*1024B + lane*16B
    __shared__ float Tls[3072];      // 12 KB: ns | nscs | ts (permuted f4 tables)

    const int tid = threadIdx.x;
    const int lane = tid & 63;
    const int l15 = lane & 15;
    const int g4 = lane >> 4;
    const int w = tid >> 6;                    // 0..3
    const int qb = blockIdx.x * 128 + w * 32;  // 32 rows per wave

    // per STAGE: 4 gload16 per wave (2 KB of C + 2 KB of W)
#define STAGE(ci, slot) do {                                                       \
        const char* _cs = cfrag8 + (size_t)(ci) * 8192 + w * 2048 + lane * 16;     \
        gload16(_cs,        &Cb8[(slot)][w * 2048]);                               \
        gload16(_cs + 1024, &Cb8[(slot)][w * 2048 + 1024]);                        \
        const char* _ws = (const char*)wfrag + (size_t)(ci) * 8192 + w * 2048 + lane * 16; \
        gload16(_ws,        (char*)&Wb[(slot)][0] + w * 2048);                     \
        gload16(_ws + 1024, (char*)&Wb[(slot)][0] + w * 2048 + 1024);              \
    } while (0)

    // ---- prologue: stage chunks 0..2; tables -> LDS; X -> fp8 regs ----
    STAGE(0, 0);
    STAGE(1, 1);
    STAGE(2, 2);

    ((float4*)Tls)[tid]       = ((const float4*)nsp)[tid];     // 256 f4 each
    ((float4*)Tls)[256 + tid] = ((const float4*)nscsp)[tid];
    ((float4*)Tls)[512 + tid] = ((const float4*)tsp)[tid];

    long xq8[2][8];
    float xs[2];
    #pragma unroll
    for (int t = 0; t < 2; ++t) {
        const float* xr = x + (size_t)(qb + t * 16 + l15) * 256 + g4 * 8;
        float ss = 0.f;
        #pragma unroll
        for (int ks = 0; ks < 8; ++ks) {
            const float4 a = *(const float4*)(xr + ks * 32);
            const float4 b = *(const float4*)(xr + ks * 32 + 4);
            ss += a.x*a.x + a.y*a.y + a.z*a.z + a.w*a.w
                + b.x*b.x + b.y*b.y + b.z*b.z + b.w*b.w;
            xq8[t][ks] = pack8_e4m3(a, b);
        }
        ss += __shfl_xor(ss, 16, 64);
        ss += __shfl_xor(ss, 32, 64);
        xs[t] = ss;
    }

    f32x4 acc[2][8];
    #pragma unroll
    for (int t = 0; t < 2; ++t)
        #pragma unroll
        for (int ot = 0; ot < 8; ++ot) acc[t][ot] = (f32x4){0.f, 0.f, 0.f, 0.f};

    __syncthreads();   // prologue-only full drain (stage 0-2, X loads, table writes)

    for (int c = 0; c < 32; ++c) {
        const int slot = c & 3;
        if (c < 29) STAGE(c + 3, (c + 3) & 3);

        // ---- S: 8 k-steps x {2 halves x 2 tiles} fp8 MFMA (A shared across tiles) ----
        f32x4 s00 = (f32x4){0.f,0.f,0.f,0.f}, s01 = s00, s10 = s00, s11 = s00;
        {
            const char* cb = &Cb8[slot][0] + (size_t)lane * 8;
            __builtin_amdgcn_s_setprio(1);
            #pragma unroll
            for (int ks = 0; ks < 8; ++ks) {
                const long A0 = *(const long*)(cb + ks * 512);
                const long A1 = *(const long*)(cb + 4096 + ks * 512);
                s00 = __builtin_amdgcn_mfma_f32_16x16x32_fp8_fp8(A0, xq8[0][ks], s00, 0, 0, 0);
                s10 = __builtin_amdgcn_mfma_f32_16x16x32_fp8_fp8(A0, xq8[1][ks], s10, 0, 0, 0);
                s01 = __builtin_amdgcn_mfma_f32_16x16x32_fp8_fp8(A1, xq8[0][ks], s01, 0, 0, 0);
                s11 = __builtin_amdgcn_mfma_f32_16x16x32_fp8_fp8(A1, xq8[1][ks], s11, 0, 0, 0);
            }
            __builtin_amdgcn_s_setprio(0);
        }

        // ---- phi = exp2(ts*S + ns*xs + nscs); tables via ds_read (lgkm domain) ----
        const int base0 = (c * 2 + 0) * 4 + g4;
        const int base1 = (c * 2 + 1) * 4 + g4;
        const float4 n0 = ((const float4*)Tls)[base0];
        const float4 q0 = ((const float4*)Tls)[256 + base0];
        const float4 t0 = ((const float4*)Tls)[512 + base0];
        const float4 n1 = ((const float4*)Tls)[base1];
        const float4 q1 = ((const float4*)Tls)[256 + base1];
        const float4 t1 = ((const float4*)Tls)[512 + base1];
        const float* n0p = (const float*)&n0; const float* q0p = (const float*)&q0;
        const float* t0p = (const float*)&t0; const float* n1p = (const float*)&n1;
        const float* q1p = (const float*)&q1; const float* t1p = (const float*)&t1;

        union { u32 u[4]; bf16x8 v; } pa0, pa1;
        {
            float p00[4], p01[4], p10[4], p11[4];
            #pragma unroll
            for (int j = 0; j < 4; ++j) {
                p00[j] = EXP2(fmaf(t0p[j], s00[j], fmaf(n0p[j], xs[0], q0p[j])));
                p01[j] = EXP2(fmaf(t1p[j], s01[j], fmaf(n1p[j], xs[0], q1p[j])));
                p10[j] = EXP2(fmaf(t0p[j], s10[j], fmaf(n0p[j], xs[1], q0p[j])));
                p11[j] = EXP2(fmaf(t1p[j], s11[j], fmaf(n1p[j], xs[1], q1p[j])));
            }
            pa0.u[0] = pack_bf16_trunc(p00[0], p00[1]);
            pa0.u[1] = pack_bf16_trunc(p00[2], p00[3]);
            pa0.u[2] = pack_bf16_trunc(p01[0], p01[1]);
            pa0.u[3] = pack_bf16_trunc(p01[2], p01[3]);
            pa1.u[0] = pack_bf16_trunc(p10[0], p10[1]);
            pa1.u[1] = pack_bf16_trunc(p10[2], p10[3]);
            pa1.u[2] = pack_bf16_trunc(p11[0], p11[1]);
            pa1.u[3] = pack_bf16_trunc(p11[2], p11[3]);
        }

        // ---- PV: 8 W-frag reads feed 16 bf16 MFMAs (W shared across tiles) ----
        {
            const bf16x8* wbl = (const bf16x8*)&Wb[slot][0] + lane;
            __builtin_amdgcn_s_setprio(1);
            #pragma unroll
            for (int ot = 0; ot < 8; ++ot) {
                const bf16x8 wv = wbl[ot * 64];
                acc[0][ot] = __builtin_amdgcn_mfma_f32_16x16x32_bf16(pa0.v, wv, acc[0][ot], 0, 0, 0);
                acc[1][ot] = __builtin_amdgcn_mfma_f32_16x16x32_bf16(pa1.v, wv, acc[1][ot], 0, 0, 0);
            }
            __builtin_amdgcn_s_setprio(0);
        }

        // ---- counted wait (T4): only STAGE loads live in vmcnt now ----
        if (c < 29)       asm volatile("s_waitcnt vmcnt(8)" ::: "memory");
        else if (c == 29) asm volatile("s_waitcnt vmcnt(4)" ::: "memory");
        else if (c == 30) asm volatile("s_waitcnt vmcnt(0)" ::: "memory");
        if (c < 31) __builtin_amdgcn_s_barrier();
    }

    // ---- epilogue: D layout col=l15 (o-sub), row=g4*4+jr (q-sub) ----
    #pragma unroll
    for (int t = 0; t < 2; ++t) {
        #pragma unroll
        for (int jr = 0; jr < 4; ++jr) {
            const int q = qb + t * 16 + g4 * 4 + jr;
            #pragma unroll
            for (int ot = 0; ot < 8; ++ot)
                out[(size_t)q * 128 + ot * 16 + l15] = acc[t][ot][jr] + bvec[ot * 16 + l15];
        }
    }
#undef STAGE
}

extern "C" void kernel_launch(void* const* d_in, const int* in_sizes, int n_in,
                              void* d_out, int out_size, void* d_ws, size_t ws_size,
                              hipStream_t stream) {
    (void)in_sizes; (void)n_in; (void)out_size; (void)ws_size;
    const float* x       = (const float*)d_in[0];
    const float* centers = (const float*)d_in[1];
    const float* sigmas  = (const float*)d_in[2];
    const float* W       = (const float*)d_in[3];
    const float* b       = (const float*)d_in[4];
    float* out = (float*)d_out;

    char*  cfrag8 = (char*)d_ws;                     // 32768 slots * 8B  = 256 KB
    short* wfrag  = (short*)(cfrag8 + 32768 * 8);    // 16384 slots * 16B = 256 KB
    float* nsp    = (float*)(wfrag + 16384 * 8);     // 4 KB
    float* nscsp  = nsp + 1024;                      // 4 KB
    float* tsp    = nscsp + 1024;                    // 4 KB

    rbf_prep<<<448, 256, 0, stream>>>(centers, sigmas, W, cfrag8, wfrag, nsp, nscsp, tsp);
    rbf_main<<<512, 256, 0, stream>>>(x, b, cfrag8, wfrag, nsp, nscsp, tsp, out);
}

// Round 12
// 70.357 us; speedup vs baseline: 7.0096x; 1.0126x over previous
//
#include <hip/hip_runtime.h>

typedef __attribute__((ext_vector_type(8))) short bf16x8;
typedef __attribute__((ext_vector_type(4))) float f32x4;
typedef unsigned int u32;
typedef unsigned long long u64;

#define LOG2E 1.44269504088896f

__device__ __forceinline__ short f2bf(float f) {
    union { float f; unsigned u; } v; v.f = f;
    unsigned r = v.u + 0x7fffu + ((v.u >> 16) & 1u);
    return (short)(r >> 16);
}

// float -> OCP e4m3fn byte (RNE, saturate to 448)
__device__ __forceinline__ u32 f2e4m3(float f) {
    u32 u = __float_as_uint(f);
    u32 sgn = (u >> 24) & 0x80u;
    u32 mag = u & 0x7fffffffu;
    if (mag >= 0x43E00000u) return sgn | 0x7Eu;
    if (mag < 0x3C800000u) {
        u32 q = (u32)(__uint_as_float(mag) * 512.0f + 0.5f);
        return sgn | q;
    }
    u32 r = mag + 0x0007FFFFu + ((mag >> 20) & 1u);
    u32 e8 = ((r >> 23) - 120u) & 0xFu;
    u32 m3 = (r >> 20) & 7u;
    return sgn | (e8 << 3) | m3;
}

__device__ __forceinline__ long pack8_e4m3(float4 a, float4 b) {
    u32 lo = f2e4m3(a.x) | (f2e4m3(a.y) << 8) | (f2e4m3(a.z) << 16) | (f2e4m3(a.w) << 24);
    u32 hi = f2e4m3(b.x) | (f2e4m3(b.y) << 8) | (f2e4m3(b.z) << 16) | (f2e4m3(b.w) << 24);
    return (long)(((u64)hi << 32) | lo);
}

#if __has_builtin(__builtin_amdgcn_exp2f)
#define EXP2(x) __builtin_amdgcn_exp2f(x)
#else
#define EXP2(x) __builtin_exp2f(x)
#endif

__device__ __forceinline__ u32 pack_bf16_trunc(float lo, float hi) {
#if __has_builtin(__builtin_amdgcn_perm)
    return __builtin_amdgcn_perm(__float_as_uint(hi), __float_as_uint(lo), 0x07060302u);
#else
    return (__float_as_uint(hi) & 0xFFFF0000u) | (__float_as_uint(lo) >> 16);
#endif
}

__device__ __forceinline__ void gload16(const void* g, void* l) {
    __builtin_amdgcn_global_load_lds(
        (const __attribute__((address_space(1))) void*)g,
        (__attribute__((address_space(3))) void*)l, 16, 0, 0);
}

// ---------------- prep (verbatim r9-r11; absmax 0.0 verified) ----------------
__global__ __launch_bounds__(256) void rbf_prep(
    const float* __restrict__ centers, const float* __restrict__ sigmas,
    const float* __restrict__ W,
    char* __restrict__ cfrag8, short* __restrict__ wfrag,
    float* __restrict__ nsp, float* __restrict__ nscsp, float* __restrict__ tsp)
{
    const int tid = threadIdx.x;
    const int bid = blockIdx.x;
    if (bid < 256) {
        const int lane = tid & 63, w = tid >> 6;
        const int m = bid * 4 + w;
        const float4 v = ((const float4*)(centers + (size_t)m * 256))[lane];
        float s = v.x*v.x + v.y*v.y + v.z*v.z + v.w*v.w;
        #pragma unroll
        for (int off = 32; off >= 1; off >>= 1) s += __shfl_xor(s, off, 64);
        if (lane == 0) {
            const float sg = sigmas[m];
            const int c = m >> 5, w5 = m & 31;
            const int g = w5 >> 3, r = w5 & 7, h = r >> 2, j = r & 3;
            const int slot = ((c * 2 + h) * 4 + g) * 4 + j;
            nsp[slot]   = -sg * LOG2E;
            nscsp[slot] = -sg * s * LOG2E;
            tsp[slot]   = 2.0f * sg * LOG2E;
        }
    } else if (bid < 384) {
        const int s = (bid - 256) * 256 + tid;               // 0..32767
        const int c = s >> 10, h = (s >> 9) & 1, ks = (s >> 6) & 7, lane = s & 63;
        const int l15 = lane & 15;
        const int m = c * 32 + 8 * (l15 >> 2) + 4 * h + (l15 & 3);
        const int k = ks * 32 + (lane >> 4) * 8;
        const float4 a = *(const float4*)(centers + (size_t)m * 256 + k);
        const float4 b = *(const float4*)(centers + (size_t)m * 256 + k + 4);
        *(long*)(cfrag8 + (size_t)s * 8) = pack8_e4m3(a, b);
    } else {
        const int s = (bid - 384) * 256 + tid;               // 0..16383
        const int c = s >> 9, ot = (s >> 6) & 7, lane = s & 63;
        const int o = ot * 16 + (lane & 15);
        const int k = c * 32 + (lane >> 4) * 8;
        const float4 a = *(const float4*)(W + (size_t)o * 1024 + k);
        const float4 b = *(const float4*)(W + (size_t)o * 1024 + k + 4);
        bf16x8 t;
        t[0]=f2bf(a.x); t[1]=f2bf(a.y); t[2]=f2bf(a.z); t[3]=f2bf(a.w);
        t[4]=f2bf(b.x); t[5]=f2bf(b.y); t[6]=f2bf(b.z); t[7]=f2bf(b.w);
        ((bf16x8*)wfrag)[s] = t;
    }
}

// ---------------- main: r11 clean-vmcnt skeleton + one-chunk defer pipeline ----------------
// 512 blocks x 256 threads, 2 blocks/CU (LDS-capped -> VGPR up to ~256 is free).
// Iter c runs S(c) [LDS ds_read + fp8 MFMA] in the same basic block as
// exp/pack/PV(c-1) [VALU + register-only bf16 MFMA, W carried in wfp regs]:
// the compiler fills the S-chain's issue gaps with independent prev-chunk work.
// Tables folded to 2 (ts, nscs): arg = fmaf(ts, S - 0.5*xs, nscs).
__global__ __launch_bounds__(256, 2) void rbf_main(
    const float* __restrict__ x, const float* __restrict__ bvec,
    const char* __restrict__ cfrag8, const short* __restrict__ wfrag,
    const float* __restrict__ nsp, const float* __restrict__ nscsp,
    const float* __restrict__ tsp, float* __restrict__ out)
{
    __shared__ char   Cb8[4][8192];   // ring: [h][ks][lane] = h*4096 + ks*512 + lane*8
    __shared__ short  Wb[4][4096];    // ring: [ot][lane]    = ot*1024B + lane*16B
    __shared__ float4 Tls[512];       // 8 KB: [0..255]=nscs(q), [256..511]=ts (permuted)

    (void)nsp;  // folded into the 2-table form

    const int tid = threadIdx.x;
    const int lane = tid & 63;
    const int l15 = lane & 15;
    const int g4 = lane >> 4;
    const int w = tid >> 6;                    // 0..3
    const int qb = blockIdx.x * 128 + w * 32;  // 32 rows per wave

#define STAGE(ci, slot) do {                                                       \
        const char* _cs = cfrag8 + (size_t)(ci) * 8192 + w * 2048 + lane * 16;     \
        gload16(_cs,        &Cb8[(slot)][w * 2048]);                               \
        gload16(_cs + 1024, &Cb8[(slot)][w * 2048 + 1024]);                        \
        const char* _ws = (const char*)wfrag + (size_t)(ci) * 8192 + w * 2048 + lane * 16; \
        gload16(_ws,        (char*)&Wb[(slot)][0] + w * 2048);                     \
        gload16(_ws + 1024, (char*)&Wb[(slot)][0] + w * 2048 + 1024);              \
    } while (0)

// S-phase MFMA chain for chunk in ring slot `sl` -> d00,d01,d10,d11
#define SCHAIN(sl, d00, d01, d10, d11) do {                                        \
        const char* cb = &Cb8[(sl)][0] + (size_t)lane * 8;                         \
        _Pragma("unroll")                                                          \
        for (int ks = 0; ks < 8; ++ks) {                                           \
            const long A0 = *(const long*)(cb + ks * 512);                         \
            const long A1 = *(const long*)(cb + 4096 + ks * 512);                  \
            d00 = __builtin_amdgcn_mfma_f32_16x16x32_fp8_fp8(A0, xq8[0][ks], d00, 0, 0, 0); \
            d10 = __builtin_amdgcn_mfma_f32_16x16x32_fp8_fp8(A0, xq8[1][ks], d10, 0, 0, 0); \
            d01 = __builtin_amdgcn_mfma_f32_16x16x32_fp8_fp8(A1, xq8[0][ks], d01, 0, 0, 0); \
            d11 = __builtin_amdgcn_mfma_f32_16x16x32_fp8_fp8(A1, xq8[1][ks], d11, 0, 0, 0); \
        }                                                                          \
    } while (0)

// deferred exp/pack/PV for chunk cm using carried S (Sp..) and W (wfp) registers
#define FINISH(cm) do {                                                            \
        const int base0 = ((cm) * 2 + 0) * 4 + g4;                                 \
        const int base1 = ((cm) * 2 + 1) * 4 + g4;                                 \
        const float4 q0 = Tls[base0];                                              \
        const float4 t0 = Tls[256 + base0];                                        \
        const float4 q1 = Tls[base1];                                              \
        const float4 t1 = Tls[256 + base1];                                        \
        const float* q0p = (const float*)&q0; const float* t0p = (const float*)&t0;\
        const float* q1p = (const float*)&q1; const float* t1p = (const float*)&t1;\
        float p00[4], p01[4], p10[4], p11[4];                                      \
        _Pragma("unroll")                                                          \
        for (int j = 0; j < 4; ++j) {                                              \
            p00[j] = EXP2(fmaf(t0p[j], Sp00[j] - hxs0, q0p[j]));                   \
            p01[j] = EXP2(fmaf(t1p[j], Sp01[j] - hxs0, q1p[j]));                   \
            p10[j] = EXP2(fmaf(t0p[j], Sp10[j] - hxs1, q0p[j]));                   \
            p11[j] = EXP2(fmaf(t1p[j], Sp11[j] - hxs1, q1p[j]));                   \
        }                                                                          \
        union { u32 u[4]; bf16x8 v; } pa0, pa1;                                    \
        pa0.u[0] = pack_bf16_trunc(p00[0], p00[1]);                                \
        pa0.u[1] = pack_bf16_trunc(p00[2], p00[3]);                                \
        pa0.u[2] = pack_bf16_trunc(p01[0], p01[1]);                                \
        pa0.u[3] = pack_bf16_trunc(p01[2], p01[3]);                                \
        pa1.u[0] = pack_bf16_trunc(p10[0], p10[1]);                                \
        pa1.u[1] = pack_bf16_trunc(p10[2], p10[3]);                                \
        pa1.u[2] = pack_bf16_trunc(p11[0], p11[1]);                                \
        pa1.u[3] = pack_bf16_trunc(p11[2], p11[3]);                                \
        _Pragma("unroll")                                                          \
        for (int ot = 0; ot < 8; ++ot) {                                           \
            acc[0][ot] = __builtin_amdgcn_mfma_f32_16x16x32_bf16(pa0.v, wfp[ot], acc[0][ot], 0, 0, 0); \
            acc[1][ot] = __builtin_amdgcn_mfma_f32_16x16x32_bf16(pa1.v, wfp[ot], acc[1][ot], 0, 0, 0); \
        }                                                                          \
    } while (0)

    // ---- prologue: stage chunks 0..2; tables -> LDS; X -> fp8 regs ----
    STAGE(0, 0);
    STAGE(1, 1);
    STAGE(2, 2);

    Tls[tid]       = ((const float4*)nscsp)[tid];
    Tls[256 + tid] = ((const float4*)tsp)[tid];

    long xq8[2][8];
    float xs[2];
    #pragma unroll
    for (int t = 0; t < 2; ++t) {
        const float* xr = x + (size_t)(qb + t * 16 + l15) * 256 + g4 * 8;
        float ss = 0.f;
        #pragma unroll
        for (int ks = 0; ks < 8; ++ks) {
            const float4 a = *(const float4*)(xr + ks * 32);
            const float4 b = *(const float4*)(xr + ks * 32 + 4);
            ss += a.x*a.x + a.y*a.y + a.z*a.z + a.w*a.w
                + b.x*b.x + b.y*b.y + b.z*b.z + b.w*b.w;
            xq8[t][ks] = pack8_e4m3(a, b);
        }
        ss += __shfl_xor(ss, 16, 64);
        ss += __shfl_xor(ss, 32, 64);
        xs[t] = ss;
    }
    const float hxs0 = 0.5f * xs[0];
    const float hxs1 = 0.5f * xs[1];

    f32x4 acc[2][8];
    #pragma unroll
    for (int t = 0; t < 2; ++t)
        #pragma unroll
        for (int ot = 0; ot < 8; ++ot) acc[t][ot] = (f32x4){0.f, 0.f, 0.f, 0.f};

    __syncthreads();   // prologue-only full drain

    // ---- peeled iter 0: STAGE(3), W(0)->wfp, S(0)->Sp ----
    STAGE(3, 3);
    bf16x8 wfp[8];
    {
        const bf16x8* wbl = (const bf16x8*)&Wb[0][0] + lane;
        #pragma unroll
        for (int f = 0; f < 8; ++f) wfp[f] = wbl[f * 64];
    }
    f32x4 Sp00 = (f32x4){0.f,0.f,0.f,0.f}, Sp01 = Sp00, Sp10 = Sp00, Sp11 = Sp00;
    __builtin_amdgcn_s_setprio(1);
    SCHAIN(0, Sp00, Sp01, Sp10, Sp11);
    __builtin_amdgcn_s_setprio(0);
    asm volatile("s_waitcnt vmcnt(8)" ::: "memory");   // chunk 1 landed
    __builtin_amdgcn_s_barrier();

    for (int c = 1; c < 32; ++c) {
        const int slot = c & 3;
        if (c < 29) STAGE(c + 3, (c + 3) & 3);

        // W(c) -> regs for NEXT iteration's deferred PV
        bf16x8 wfc[8];
        {
            const bf16x8* wbl = (const bf16x8*)&Wb[slot][0] + lane;
            #pragma unroll
            for (int f = 0; f < 8; ++f) wfc[f] = wbl[f * 64];
        }

        __builtin_amdgcn_s_setprio(1);
        // S(c) [LDS+MFMA] and FINISH(c-1) [VALU + reg-MFMA] share this block:
        // the scheduler interleaves them (independent dataflow).
        f32x4 s00 = (f32x4){0.f,0.f,0.f,0.f}, s01 = s00, s10 = s00, s11 = s00;
        SCHAIN(slot, s00, s01, s10, s11);
        FINISH(c - 1);
        __builtin_amdgcn_s_setprio(0);

        // rotate carried state
        Sp00 = s00; Sp01 = s01; Sp10 = s10; Sp11 = s11;
        #pragma unroll
        for (int f = 0; f < 8; ++f) wfp[f] = wfc[f];

        // counted waits (T4): only STAGE DMAs live in vmcnt
        if (c < 29)       asm volatile("s_waitcnt vmcnt(8)" ::: "memory");
        else if (c == 29) asm volatile("s_waitcnt vmcnt(4)" ::: "memory");
        else if (c == 30) asm volatile("s_waitcnt vmcnt(0)" ::: "memory");
        if (c < 31) __builtin_amdgcn_s_barrier();
    }

    // ---- drain: finish chunk 31 ----
    FINISH(31);

    // ---- epilogue: D layout col=l15 (o-sub), row=g4*4+jr (q-sub) ----
    #pragma unroll
    for (int t = 0; t < 2; ++t) {
        #pragma unroll
        for (int jr = 0; jr < 4; ++jr) {
            const int q = qb + t * 16 + g4 * 4 + jr;
            #pragma unroll
            for (int ot = 0; ot < 8; ++ot)
                out[(size_t)q * 128 + ot * 16 + l15] = acc[t][ot][jr] + bvec[ot * 16 + l15];
        }
    }
#undef STAGE
#undef SCHAIN
#undef FINISH
}

extern "C" void kernel_launch(void* const* d_in, const int* in_sizes, int n_in,
                              void* d_out, int out_size, void* d_ws, size_t ws_size,
                              hipStream_t stream) {
    (void)in_sizes; (void)n_in; (void)out_size; (void)ws_size;
    const float* x       = (const float*)d_in[0];
    const float* centers = (const float*)d_in[1];
    const float* sigmas  = (const float*)d_in[2];
    const float* W       = (const float*)d_in[3];
    const float* b       = (const float*)d_in[4];
    float* out = (float*)d_out;

    char*  cfrag8 = (char*)d_ws;                     // 32768 slots * 8B  = 256 KB
    short* wfrag  = (short*)(cfrag8 + 32768 * 8);    // 16384 slots * 16B = 256 KB
    float* nsp    = (float*)(wfrag + 16384 * 8);     // 4 KB
    float* nscsp  = nsp + 1024;                      // 4 KB
    float* tsp    = nscsp + 1024;                    // 4 KB

    rbf_prep<<<448, 256, 0, stream>>>(centers, sigmas, W, cfrag8, wfrag, nsp, nscsp, tsp);
    rbf_main<<<512, 256, 0, stream>>>(x, b, cfrag8, wfrag, nsp, nscsp, tsp, out);
}